// Round 11
// baseline (481.112 us; speedup 1.0000x reference)
//
#include <hip/hip_runtime.h>

#define C_IN  32
#define C_OUT 64
#define KK    27

using frag_ab = __attribute__((ext_vector_type(8))) short;  // 8 bf16
using frag_cd = __attribute__((ext_vector_type(4))) float;  // 4 fp32

static __device__ inline unsigned short f2bf(float f) {   // RTNE f32->bf16
    unsigned u = __float_as_uint(f);
    return (unsigned short)((u + 0x7fffu + ((u >> 16) & 1u)) >> 16);
}
static __device__ inline unsigned pack2(float a, float b) {
    return (unsigned)f2bf(a) | ((unsigned)f2bf(b) << 16);
}
static __device__ inline float bflo(unsigned u) { return __uint_as_float(u << 16); }
static __device__ inline float bfhi(unsigned u) { return __uint_as_float(u & 0xffff0000u); }

// ===========================================================================
// Fallback path (round-1, passing) if workspace too small
// ===========================================================================
__global__ __launch_bounds__(256) void sic_init_bias(float4* __restrict__ out4,
                                                     const float4* __restrict__ bias4,
                                                     int total4) {
    int idx = blockIdx.x * 256 + threadIdx.x, stride = gridDim.x * 256;
    for (int i = idx; i < total4; i += stride) out4[i] = bias4[i & 15];
}

__global__ __launch_bounds__(256) void sic_scatter(
    const float* __restrict__ feats, const float* __restrict__ weight,
    const int* __restrict__ bwd, const int* __restrict__ in_idx,
    const int* __restrict__ out_idx, float* __restrict__ out, int n_in)
{
    const int k = blockIdx.y, lane = threadIdx.x & 63, wid = threadIdx.x >> 6;
    float w[C_IN];
    const float* wk = weight + k * (C_IN * C_OUT);
#pragma unroll
    for (int i = 0; i < C_IN; ++i) w[i] = wk[i * C_OUT + lane];
    const int waves_total = gridDim.x * 4;
    const long long base = (long long)k * n_in;
    for (int p = blockIdx.x * 4 + wid; p < n_in; p += waves_total) {
        int src = __builtin_amdgcn_readfirstlane(in_idx[base + p]);
        int dst = __builtin_amdgcn_readfirstlane(out_idx[base + p]);
        int row = __builtin_amdgcn_readfirstlane(bwd[src]);
        const float* f = feats + (long long)row * C_IN;
        float acc = 0.0f;
#pragma unroll
        for (int i = 0; i < C_IN; ++i) acc = fmaf(f[i], w[i], acc);
        atomicAdd(out + (long long)dst * C_OUT + lane, acc);
    }
}

// ===========================================================================
// Prep kernels
// ===========================================================================
__global__ __launch_bounds__(512) void sic_zero(int* __restrict__ p, int n) {
    int i = blockIdx.x * 512 + threadIdx.x, stride = gridDim.x * 512;
    for (; i < n; i += stride) p[i] = 0;
}

// feats (f32) -> featsbf (bf16), plus one zeroed pad row at index n_in
__global__ __launch_bounds__(256) void sic_fconv(const float* __restrict__ feats,
                                                 short* __restrict__ featsbf, int n_in) {
    int t = blockIdx.x * 256 + threadIdx.x;
    if (t >= (n_in + 1) * 4) return;
    int row = t >> 2, c8 = (t & 3) * 8;
    uint4 v = {0u, 0u, 0u, 0u};
    if (row < n_in) {
        const float* fp = feats + (size_t)row * C_IN + c8;
        float4 f0 = ((const float4*)fp)[0];
        float4 f1 = ((const float4*)fp)[1];
        v.x = pack2(f0.x, f0.y);
        v.y = pack2(f0.z, f0.w);
        v.z = pack2(f1.x, f1.y);
        v.w = pack2(f1.z, f1.w);
    }
    ((uint4*)featsbf)[t] = v;
}

// weight (f32 [27][32][64]) -> bf16 fragments [27][4][64 lanes][8]
// lane l (g=l>>4, cl=l&15), block nb: elems W[k][g*8+j][nb*16+cl]
__global__ __launch_bounds__(256) void sic_wconv(const float* __restrict__ weight,
                                                 short* __restrict__ wfrag) {
    int t = blockIdx.x * 256 + threadIdx.x;
    if (t >= KK * 4 * 64) return;
    int l = t & 63, nb = (t >> 6) & 3, k = t >> 8;
    int g = l >> 4, cl = l & 15;
    const float* wp = weight + (size_t)k * (C_IN * C_OUT) + nb * 16 + cl;
    float r[8];
#pragma unroll
    for (int j = 0; j < 8; ++j) r[j] = wp[(size_t)(g * 8 + j) * C_OUT];
    uint4 v = {pack2(r[0], r[1]), pack2(r[2], r[3]), pack2(r[4], r[5]), pack2(r[6], r[7])};
    ((uint4*)wfrag)[t] = v;
}

// histogram by destination + per-record ordinal (the atomic's return value)
__global__ __launch_bounds__(256) void sic_hist3(const int* __restrict__ out_idx_seg,
                                                 int* __restrict__ count,
                                                 int* __restrict__ ord, int pseg) {
    int i = blockIdx.x * 256 + threadIdx.x;
    if (i < pseg) {
        ord[i] = atomicAdd(&count[out_idx_seg[i]], 1);  // coalesced ord write
    }
}

// ---- wide 2-level exclusive scan (2048 elems/block) ----
__global__ __launch_bounds__(512) void sic_scanA(const int* __restrict__ in,
                                                 int* __restrict__ outExcl,
                                                 int* __restrict__ sums, int n) {
    __shared__ int sm[512];
    int tid = threadIdx.x;
    int base = blockIdx.x * 2048 + tid * 4;
    int e0 = (base + 0 < n) ? in[base + 0] : 0;
    int e1 = (base + 1 < n) ? in[base + 1] : 0;
    int e2 = (base + 2 < n) ? in[base + 2] : 0;
    int e3 = (base + 3 < n) ? in[base + 3] : 0;
    int s = e0 + e1 + e2 + e3;
    sm[tid] = s;
    __syncthreads();
    for (int off = 1; off < 512; off <<= 1) {
        int t = (tid >= off) ? sm[tid - off] : 0;
        __syncthreads();
        sm[tid] += t;
        __syncthreads();
    }
    int pre = sm[tid] - s;                   // exclusive within block
    if (base + 0 < n) outExcl[base + 0] = pre;
    if (base + 1 < n) outExcl[base + 1] = pre + e0;
    if (base + 2 < n) outExcl[base + 2] = pre + e0 + e1;
    if (base + 3 < n) outExcl[base + 3] = pre + e0 + e1 + e2;
    if (tid == 511) sums[blockIdx.x] = sm[511];
}

__global__ __launch_bounds__(512) void sic_scan_small(int* __restrict__ buf, int n) {
    __shared__ int sm[512];
    int tid = threadIdx.x;
    int e = (tid < n) ? buf[tid] : 0;
    sm[tid] = e;
    __syncthreads();
    for (int off = 1; off < 512; off <<= 1) {
        int t = (tid >= off) ? sm[tid - off] : 0;
        __syncthreads();
        sm[tid] += t;
        __syncthreads();
    }
    if (tid < n) buf[tid] = sm[tid] - e;
}

__global__ __launch_bounds__(512) void sic_addbackA(int* __restrict__ arr,
                                                    const int* __restrict__ sums, int n) {
    int s = sums[blockIdx.x];
    int base = blockIdx.x * 2048 + threadIdx.x * 4;
#pragma unroll
    for (int i = 0; i < 4; ++i)
        if (base + i < n) arr[base + i] += s;
}

// ===========================================================================
// Phase A: per-k MFMA; slot = startv[dst] + ord[rec] (atomic-free).
// Per-wave LDS transpose (wave-private slice, no barrier), then each record
// stored as ONE full 128B row by 8 lanes x contiguous 16B in one instruction
// -> full-line store, no L2 read-for-ownership.
// Row layout is canonical: uint m holds channels 2m, 2m+1.
// ===========================================================================
__global__ __launch_bounds__(256) void sic_gemm5(
    const int* __restrict__ in_idx,     // global rulebook [KK][n_in]
    const int* __restrict__ out_idx,
    const int* __restrict__ bwd,
    const int* __restrict__ ord,        // segment-local [kseg*n_in]
    const int* __restrict__ startv,     // per-dst slot base
    const short* __restrict__ featsbf,  // [(n_in+pad)][32] bf16
    const short* __restrict__ wfrag,    // [KK][4][64][8] bf16
    unsigned int* __restrict__ contribU,// row r at contribU[r*32]
    int n_in, int k0, int zrow)
{
    __shared__ unsigned smU[4][16][40];   // [wave][record][32 uints + pad8]
    const int kk   = k0 + blockIdx.y;
    const int lane = threadIdx.x & 63;
    const int wid  = threadIdx.x >> 6;
    const int g = lane >> 4, cl = lane & 15;

    const frag_ab wa0 = *(const frag_ab*)(wfrag + ((size_t)(kk * 4 + 0) * 64 + lane) * 8);
    const frag_ab wa1 = *(const frag_ab*)(wfrag + ((size_t)(kk * 4 + 1) * 64 + lane) * 8);
    const frag_ab wa2 = *(const frag_ab*)(wfrag + ((size_t)(kk * 4 + 2) * 64 + lane) * 8);
    const frag_ab wa3 = *(const frag_ab*)(wfrag + ((size_t)(kk * 4 + 3) * 64 + lane) * 8);
    const frag_cd zf = {0.f, 0.f, 0.f, 0.f};

    const size_t gk  = (size_t)kk * n_in;            // rulebook base (global k)
    const size_t sk  = (size_t)blockIdx.y * n_in;    // ord base (segment-local)
    const int t      = blockIdx.x * 4 + wid;         // one 16-record tile per wave
    const int tbase  = t * 16;
    const int idx    = tbase + cl;                   // same for all g of this cl
    const bool valid = idx < n_in;

    int row = zrow, pos = 0;
    if (valid) {
        row = bwd[in_idx[gk + idx]];                 // fused feats[bwd] gather
        int dst = out_idx[gk + idx];
        pos = startv[dst] + ord[sk + idx];           // slot, no atomics
    }

    frag_ab b = *(const frag_ab*)(featsbf + (size_t)row * C_IN + g * 8);
    frag_cd d0 = __builtin_amdgcn_mfma_f32_16x16x32_bf16(wa0, b, zf, 0, 0, 0);
    frag_cd d1 = __builtin_amdgcn_mfma_f32_16x16x32_bf16(wa1, b, zf, 0, 0, 0);
    frag_cd d2 = __builtin_amdgcn_mfma_f32_16x16x32_bf16(wa2, b, zf, 0, 0, 0);
    frag_cd d3 = __builtin_amdgcn_mfma_f32_16x16x32_bf16(wa3, b, zf, 0, 0, 0);

    // transpose through wave-private LDS (b64 writes; no barrier needed)
    {
        uint2 v0 = {pack2(d0[0], d0[1]), pack2(d0[2], d0[3])};
        uint2 v1 = {pack2(d1[0], d1[1]), pack2(d1[2], d1[3])};
        uint2 v2 = {pack2(d2[0], d2[1]), pack2(d2[2], d2[3])};
        uint2 v3 = {pack2(d3[0], d3[1]), pack2(d3[2], d3[3])};
        *(uint2*)&smU[wid][cl][ 0 + g * 2] = v0;   // uints m: ch 2m,2m+1
        *(uint2*)&smU[wid][cl][ 8 + g * 2] = v1;
        *(uint2*)&smU[wid][cl][16 + g * 2] = v2;
        *(uint2*)&smU[wid][cl][24 + g * 2] = v3;
    }

    // write-out: 8 lanes per record, each one contiguous 16B chunk -> one
    // full 128B line per record per instruction
#pragma unroll
    for (int p2 = 0; p2 < 2; ++p2) {
        int r = (lane >> 3) + p2 * 8;         // record 0..15
        int c = lane & 7;                     // 16B chunk 0..7
        uint4 v = {smU[wid][r][c * 4 + 0], smU[wid][r][c * 4 + 1],
                   smU[wid][r][c * 4 + 2], smU[wid][r][c * 4 + 3]};
        int pos_r = __shfl(pos, r, 64);       // lane r (g=0, cl=r) holds pos
        if (tbase + r < n_in) {
            *(uint4*)(contribU + (size_t)pos_r * 32 + c * 4) = v;
        }
    }
}

// ===========================================================================
// Phase B: streaming reduce, half-wave (32 lanes) per dst = one 128B row
// read per contributor per instruction; divergence across only 2 runs/wave.
// Lane q owns uint column q = channels 2q, 2q+1; float2 out-write.
// ===========================================================================
__global__ __launch_bounds__(256) void sic_reduce6(
    const unsigned int* __restrict__ contribU,  // row r at contribU[r*32]
    const int* __restrict__ startv, const int* __restrict__ count,
    const float* __restrict__ bias, float* __restrict__ out,
    int n_out, int first)
{
    int wave = (blockIdx.x * 256 + threadIdx.x) >> 6;
    int l = threadIdx.x & 63;
    int h = l >> 5, q = l & 31;
    int dst = wave * 2 + h;
    if (dst >= n_out) return;
    int s = startv[dst], c = count[dst];
    int ch = q * 2;

    float a0, a1;
    if (first) {
        float2 bv = *(const float2*)(bias + ch);
        a0 = bv.x; a1 = bv.y;
    } else {
        float2 ov = *(const float2*)(out + (size_t)dst * C_OUT + ch);
        a0 = ov.x; a1 = ov.y;
    }
    const unsigned int* p = contribU + (size_t)s * 32 + q;
    for (int j = 0; j < c; ++j) {
        unsigned u = __builtin_nontemporal_load(p + (size_t)j * 32);
        a0 += bflo(u); a1 += bfhi(u);
    }
    float2 v = {a0, a1};
    *(float2*)(out + (size_t)dst * C_OUT + ch) = v;
}

// ===========================================================================
extern "C" void kernel_launch(void* const* d_in, const int* in_sizes, int n_in_cnt,
                              void* d_out, int out_size, void* d_ws, size_t ws_size,
                              hipStream_t stream) {
    const float* feats   = (const float*)d_in[0];
    const float* weight  = (const float*)d_in[1];
    const float* bias    = (const float*)d_in[2];
    const int*   bwd     = (const int*)d_in[3];
    const int*   in_idx  = (const int*)d_in[4];
    const int*   out_idx = (const int*)d_in[5];
    float*       out     = (float*)d_out;

    const int n_in  = in_sizes[0] / C_IN;      // 100000
    const int n_out = out_size / C_OUT;        // 800000
    const size_t P  = (size_t)KK * n_in;       // 2.7M records

    const int NCHA = (n_out + 2047) / 2048;    // 391 scan chunks

    // ---- workspace layout (int units) ----
    const size_t NOUTr   = ((size_t)n_out + 255) & ~(size_t)255;
    const size_t o_cnt   = 0;
    const size_t o_stv   = NOUTr;
    const size_t o_s1    = 2 * NOUTr;                    // sums (NCHA <= 512)
    const size_t o_ord   = (o_s1 + 512 + 255) & ~(size_t)255;      // ord (P)
    const size_t o_fbf   = (o_ord + P + 255) & ~(size_t)255;
    const size_t fbf_i   = ((size_t)(n_in + 16) * C_IN * 2 + 3) / 4;
    const size_t o_wfr   = (o_fbf + fbf_i + 255) & ~(size_t)255;
    const size_t wfr_i   = (size_t)KK * 4 * 64 * 8 * 2 / 4;
    const size_t o_ctr   = (o_wfr + wfr_i + 255) & ~(size_t)255;   // contrib

    const size_t ws_ints = ws_size / 4;
    size_t cap_recs = (ws_ints > o_ctr) ? (ws_ints - o_ctr) / 32 : 0;  // 128B/rec
    int kseg_max = (int)(cap_recs / (size_t)n_in);
    if (kseg_max > KK) kseg_max = KK;

    if (kseg_max < 1 || NCHA > 512) {
        // fallback: round-1 atomic path
        const int total4 = out_size / 4;
        hipLaunchKernelGGL(sic_init_bias, dim3(2048), dim3(256), 0, stream,
                           (float4*)out, (const float4*)bias, total4);
        hipLaunchKernelGGL(sic_scatter, dim3(160, KK), dim3(256), 0, stream,
                           feats, weight, bwd, in_idx, out_idx, out, n_in);
        return;
    }

    int* ws = (int*)d_ws;
    int* count  = ws + o_cnt;
    int* startv = ws + o_stv;
    int* sums   = ws + o_s1;
    int* ord    = ws + o_ord;
    short* featsbf = (short*)(ws + o_fbf);
    short* wfrag   = (short*)(ws + o_wfr);
    unsigned int* contribU = (unsigned int*)(ws + o_ctr);

    // one-time conversions
    hipLaunchKernelGGL(sic_fconv, dim3(((n_in + 1) * 4 + 255) / 256), dim3(256), 0, stream,
                       feats, featsbf, n_in);
    hipLaunchKernelGGL(sic_wconv, dim3((KK * 4 * 64 + 255) / 256), dim3(256), 0, stream,
                       weight, wfrag);

    const int ntiles  = (n_in + 15) / 16;
    const int gx_gemm = (ntiles + 3) / 4;      // one tile per wave

    // reduce grid: half-wave per dst (2 dsts per wave, 4 waves per block)
    const int nwaves_red = (n_out + 1) / 2;
    const int gx_red = (nwaves_red + 3) / 4;

    // segment loop over k (single pass when contrib fits: kseg_max == 27)
    for (int k0 = 0; k0 < KK; k0 += kseg_max) {
        const int kseg = (KK - k0 < kseg_max) ? (KK - k0) : kseg_max;
        const int pseg = kseg * n_in;
        const int gp   = (pseg + 255) / 256;
        const int* oseg = out_idx + (size_t)k0 * n_in;

        hipLaunchKernelGGL(sic_zero, dim3(1024), dim3(512), 0, stream, count, n_out);
        hipLaunchKernelGGL(sic_hist3, dim3(gp), dim3(256), 0, stream,
                           oseg, count, ord, pseg);
        hipLaunchKernelGGL(sic_scanA, dim3(NCHA), dim3(512), 0, stream,
                           count, startv, sums, n_out);
        hipLaunchKernelGGL(sic_scan_small, dim3(1), dim3(512), 0, stream, sums, NCHA);
        hipLaunchKernelGGL(sic_addbackA, dim3(NCHA), dim3(512), 0, stream,
                           startv, sums, n_out);
        // MFMA + LDS transpose + full-line dst-sorted row scatter (atomic-free)
        hipLaunchKernelGGL(sic_gemm5, dim3(gx_gemm, kseg), dim3(256), 0, stream,
                           in_idx, out_idx, bwd, ord, startv,
                           featsbf, wfrag, contribU, n_in, k0, n_in);
        // streaming reduce: half-wave per output row
        hipLaunchKernelGGL(sic_reduce6, dim3(gx_red), dim3(256), 0, stream,
                           contribU, startv, count, bias, out,
                           n_out, (k0 == 0) ? 1 : 0);
    }
}

// Round 12
// 354.396 us; speedup vs baseline: 1.3576x; 1.3576x over previous
//
#include <hip/hip_runtime.h>

#define C_IN  32
#define C_OUT 64
#define KK    27

using frag_ab = __attribute__((ext_vector_type(8))) short;  // 8 bf16
using frag_cd = __attribute__((ext_vector_type(4))) float;  // 4 fp32
using u32x4   = __attribute__((ext_vector_type(4))) unsigned int;  // nt-able

static __device__ inline unsigned short f2bf(float f) {   // RTNE f32->bf16
    unsigned u = __float_as_uint(f);
    return (unsigned short)((u + 0x7fffu + ((u >> 16) & 1u)) >> 16);
}
static __device__ inline unsigned pack2(float a, float b) {
    return (unsigned)f2bf(a) | ((unsigned)f2bf(b) << 16);
}
static __device__ inline float bflo(unsigned u) { return __uint_as_float(u << 16); }
static __device__ inline float bfhi(unsigned u) { return __uint_as_float(u & 0xffff0000u); }

// ===========================================================================
// Fallback path (round-1, passing) if workspace too small
// ===========================================================================
__global__ __launch_bounds__(256) void sic_init_bias(float4* __restrict__ out4,
                                                     const float4* __restrict__ bias4,
                                                     int total4) {
    int idx = blockIdx.x * 256 + threadIdx.x, stride = gridDim.x * 256;
    for (int i = idx; i < total4; i += stride) out4[i] = bias4[i & 15];
}

__global__ __launch_bounds__(256) void sic_scatter(
    const float* __restrict__ feats, const float* __restrict__ weight,
    const int* __restrict__ bwd, const int* __restrict__ in_idx,
    const int* __restrict__ out_idx, float* __restrict__ out, int n_in)
{
    const int k = blockIdx.y, lane = threadIdx.x & 63, wid = threadIdx.x >> 6;
    float w[C_IN];
    const float* wk = weight + k * (C_IN * C_OUT);
#pragma unroll
    for (int i = 0; i < C_IN; ++i) w[i] = wk[i * C_OUT + lane];
    const int waves_total = gridDim.x * 4;
    const long long base = (long long)k * n_in;
    for (int p = blockIdx.x * 4 + wid; p < n_in; p += waves_total) {
        int src = __builtin_amdgcn_readfirstlane(in_idx[base + p]);
        int dst = __builtin_amdgcn_readfirstlane(out_idx[base + p]);
        int row = __builtin_amdgcn_readfirstlane(bwd[src]);
        const float* f = feats + (long long)row * C_IN;
        float acc = 0.0f;
#pragma unroll
        for (int i = 0; i < C_IN; ++i) acc = fmaf(f[i], w[i], acc);
        atomicAdd(out + (long long)dst * C_OUT + lane, acc);
    }
}

// ===========================================================================
// Prep kernels
// ===========================================================================
__global__ __launch_bounds__(512) void sic_zero(int* __restrict__ p, int n) {
    int i = blockIdx.x * 512 + threadIdx.x, stride = gridDim.x * 512;
    for (; i < n; i += stride) p[i] = 0;
}

// feats (f32) -> featsbf (bf16), plus one zeroed pad row at index n_in
__global__ __launch_bounds__(256) void sic_fconv(const float* __restrict__ feats,
                                                 short* __restrict__ featsbf, int n_in) {
    int t = blockIdx.x * 256 + threadIdx.x;
    if (t >= (n_in + 1) * 4) return;
    int row = t >> 2, c8 = (t & 3) * 8;
    uint4 v = {0u, 0u, 0u, 0u};
    if (row < n_in) {
        const float* fp = feats + (size_t)row * C_IN + c8;
        float4 f0 = ((const float4*)fp)[0];
        float4 f1 = ((const float4*)fp)[1];
        v.x = pack2(f0.x, f0.y);
        v.y = pack2(f0.z, f0.w);
        v.z = pack2(f1.x, f1.y);
        v.w = pack2(f1.z, f1.w);
    }
    ((uint4*)featsbf)[t] = v;
}

// weight (f32 [27][32][64]) -> bf16 fragments [27][4][64 lanes][8]
// lane l (g=l>>4, cl=l&15), block nb: elems W[k][g*8+j][nb*16+cl]
__global__ __launch_bounds__(256) void sic_wconv(const float* __restrict__ weight,
                                                 short* __restrict__ wfrag) {
    int t = blockIdx.x * 256 + threadIdx.x;
    if (t >= KK * 4 * 64) return;
    int l = t & 63, nb = (t >> 6) & 3, k = t >> 8;
    int g = l >> 4, cl = l & 15;
    const float* wp = weight + (size_t)k * (C_IN * C_OUT) + nb * 16 + cl;
    float r[8];
#pragma unroll
    for (int j = 0; j < 8; ++j) r[j] = wp[(size_t)(g * 8 + j) * C_OUT];
    uint4 v = {pack2(r[0], r[1]), pack2(r[2], r[3]), pack2(r[4], r[5]), pack2(r[6], r[7])};
    ((uint4*)wfrag)[t] = v;
}

// histogram by destination + per-record ordinal (the atomic's return value)
__global__ __launch_bounds__(256) void sic_hist3(const int* __restrict__ out_idx_seg,
                                                 int* __restrict__ count,
                                                 int* __restrict__ ord, int pseg) {
    int i = blockIdx.x * 256 + threadIdx.x;
    if (i < pseg) {
        ord[i] = atomicAdd(&count[out_idx_seg[i]], 1);  // coalesced ord write
    }
}

// ---- wide 2-level exclusive scan (2048 elems/block) ----
__global__ __launch_bounds__(512) void sic_scanA(const int* __restrict__ in,
                                                 int* __restrict__ outExcl,
                                                 int* __restrict__ sums, int n) {
    __shared__ int sm[512];
    int tid = threadIdx.x;
    int base = blockIdx.x * 2048 + tid * 4;
    int e0 = (base + 0 < n) ? in[base + 0] : 0;
    int e1 = (base + 1 < n) ? in[base + 1] : 0;
    int e2 = (base + 2 < n) ? in[base + 2] : 0;
    int e3 = (base + 3 < n) ? in[base + 3] : 0;
    int s = e0 + e1 + e2 + e3;
    sm[tid] = s;
    __syncthreads();
    for (int off = 1; off < 512; off <<= 1) {
        int t = (tid >= off) ? sm[tid - off] : 0;
        __syncthreads();
        sm[tid] += t;
        __syncthreads();
    }
    int pre = sm[tid] - s;                   // exclusive within block
    if (base + 0 < n) outExcl[base + 0] = pre;
    if (base + 1 < n) outExcl[base + 1] = pre + e0;
    if (base + 2 < n) outExcl[base + 2] = pre + e0 + e1;
    if (base + 3 < n) outExcl[base + 3] = pre + e0 + e1 + e2;
    if (tid == 511) sums[blockIdx.x] = sm[511];
}

__global__ __launch_bounds__(512) void sic_scan_small(int* __restrict__ buf, int n) {
    __shared__ int sm[512];
    int tid = threadIdx.x;
    int e = (tid < n) ? buf[tid] : 0;
    sm[tid] = e;
    __syncthreads();
    for (int off = 1; off < 512; off <<= 1) {
        int t = (tid >= off) ? sm[tid - off] : 0;
        __syncthreads();
        sm[tid] += t;
        __syncthreads();
    }
    if (tid < n) buf[tid] = sm[tid] - e;
}

__global__ __launch_bounds__(512) void sic_addbackA(int* __restrict__ arr,
                                                    const int* __restrict__ sums, int n) {
    int s = sums[blockIdx.x];
    int base = blockIdx.x * 2048 + threadIdx.x * 4;
#pragma unroll
    for (int i = 0; i < 4; ++i)
        if (base + i < n) arr[base + i] += s;
}

// ===========================================================================
// Phase A (round-9 gemm3, verbatim — proven 144us): per-k MFMA;
// slot = startv[dst] + ord[rec]; LDS transpose; nt-store 128B rows.
// ===========================================================================
__global__ __launch_bounds__(256) void sic_gemm3(
    const int* __restrict__ in_idx,     // global rulebook [KK][n_in]
    const int* __restrict__ out_idx,
    const int* __restrict__ bwd,
    const int* __restrict__ ord,        // segment-local [kseg*n_in]
    const int* __restrict__ startv,     // per-dst slot base
    const short* __restrict__ featsbf,  // [(n_in+pad)][32] bf16
    const short* __restrict__ wfrag,    // [KK][4][64][8] bf16
    unsigned short* __restrict__ contrib,
    int n_in, int k0, int zrow)
{
    __shared__ unsigned smU[4][16][40];   // [wave][record][32 uints + pad8]
    const int kk   = k0 + blockIdx.y;
    const int lane = threadIdx.x & 63;
    const int wid  = threadIdx.x >> 6;
    const int g = lane >> 4, cl = lane & 15;

    const frag_ab wa0 = *(const frag_ab*)(wfrag + ((size_t)(kk * 4 + 0) * 64 + lane) * 8);
    const frag_ab wa1 = *(const frag_ab*)(wfrag + ((size_t)(kk * 4 + 1) * 64 + lane) * 8);
    const frag_ab wa2 = *(const frag_ab*)(wfrag + ((size_t)(kk * 4 + 2) * 64 + lane) * 8);
    const frag_ab wa3 = *(const frag_ab*)(wfrag + ((size_t)(kk * 4 + 3) * 64 + lane) * 8);
    const frag_cd zf = {0.f, 0.f, 0.f, 0.f};

    const size_t gk  = (size_t)kk * n_in;            // rulebook base (global k)
    const size_t sk  = (size_t)blockIdx.y * n_in;    // ord base (segment-local)
    const int t      = blockIdx.x * 4 + wid;         // one 16-record tile per wave
    const int tbase  = t * 16;
    const int idx    = tbase + cl;
    const bool valid = idx < n_in;

    int row = zrow, pos = 0;
    if (valid) {
        row = bwd[in_idx[gk + idx]];                 // fused feats[bwd] gather
        int dst = out_idx[gk + idx];
        pos = startv[dst] + ord[sk + idx];           // slot, no atomics
    }

    frag_ab b = *(const frag_ab*)(featsbf + (size_t)row * C_IN + g * 8);
    frag_cd d0 = __builtin_amdgcn_mfma_f32_16x16x32_bf16(wa0, b, zf, 0, 0, 0);
    frag_cd d1 = __builtin_amdgcn_mfma_f32_16x16x32_bf16(wa1, b, zf, 0, 0, 0);
    frag_cd d2 = __builtin_amdgcn_mfma_f32_16x16x32_bf16(wa2, b, zf, 0, 0, 0);
    frag_cd d3 = __builtin_amdgcn_mfma_f32_16x16x32_bf16(wa3, b, zf, 0, 0, 0);

    // transpose through LDS: record-major rows of 32 uints (64 bf16 ch)
    smU[wid][cl][0  + g * 2 + 0] = pack2(d0[0], d0[1]);
    smU[wid][cl][0  + g * 2 + 1] = pack2(d0[2], d0[3]);
    smU[wid][cl][8  + g * 2 + 0] = pack2(d1[0], d1[1]);
    smU[wid][cl][8  + g * 2 + 1] = pack2(d1[2], d1[3]);
    smU[wid][cl][16 + g * 2 + 0] = pack2(d2[0], d2[1]);
    smU[wid][cl][16 + g * 2 + 1] = pack2(d2[2], d2[3]);
    smU[wid][cl][24 + g * 2 + 0] = pack2(d3[0], d3[1]);
    smU[wid][cl][24 + g * 2 + 1] = pack2(d3[2], d3[3]);
    __syncthreads();

    // write-out: 8 lanes per record, each lane one 16B chunk -> 128B/row
#pragma unroll
    for (int p = 0; p < 2; ++p) {
        int r = (lane >> 3) + p * 8;          // record 0..15
        int c = lane & 7;                     // 16B chunk 0..7
        u32x4 v = {smU[wid][r][c * 4 + 0], smU[wid][r][c * 4 + 1],
                   smU[wid][r][c * 4 + 2], smU[wid][r][c * 4 + 3]};
        int pos_r = __shfl(pos, r, 64);       // pos lives at any lane with cl==r
        if (tbase + r < n_in) {
            __builtin_nontemporal_store(v,
                (u32x4*)(contrib + (size_t)pos_r * C_OUT + c * 8));
        }
    }
}

// ===========================================================================
// Phase B: streaming reduce, clamped-quad ILP. 8 threads/dst, thread c8 owns
// 16B chunk c8 (channels 8*c8..8*c8+7). Per batch: 4 UNCONDITIONAL independent
// nt loads at clamped indices (slots contiguous -> always valid), masked
// accumulate. Typical c<=4 completes in one 4-parallel batch.
// ===========================================================================
__global__ __launch_bounds__(256) void sic_reduce8(
    const unsigned int* __restrict__ contribU,  // row r at contribU[r*32]
    const int* __restrict__ startv, const int* __restrict__ count,
    const float* __restrict__ bias, float* __restrict__ out,
    int n_out, int first)
{
    int t = blockIdx.x * 256 + threadIdx.x;
    int dst = t >> 3, c8 = t & 7;
    if (dst >= n_out) return;
    int s = startv[dst], c = count[dst];

    size_t ob = (size_t)dst * C_OUT + c8 * 8;
    float4 a0, a1;
    if (first) {
        a0 = *(const float4*)(bias + c8 * 8);
        a1 = *(const float4*)(bias + c8 * 8 + 4);
    } else {
        a0 = *(const float4*)(out + ob);
        a1 = *(const float4*)(out + ob + 4);
    }
    const u32x4* p = (const u32x4*)(contribU + (size_t)s * 32) + c8;
    for (int j = 0; j < c; j += 4) {
        int cm = c - 1;
        int j1 = (j + 1 < cm) ? j + 1 : cm;
        int j2 = (j + 2 < cm) ? j + 2 : cm;
        int j3 = (j + 3 < cm) ? j + 3 : cm;
        // 4 independent loads issued together (duplicates hit L1)
        u32x4 v0 = __builtin_nontemporal_load(&p[(size_t)j  * 8]);
        u32x4 v1 = __builtin_nontemporal_load(&p[(size_t)j1 * 8]);
        u32x4 v2 = __builtin_nontemporal_load(&p[(size_t)j2 * 8]);
        u32x4 v3 = __builtin_nontemporal_load(&p[(size_t)j3 * 8]);
        a0.x += bflo(v0.x); a0.y += bfhi(v0.x);
        a0.z += bflo(v0.y); a0.w += bfhi(v0.y);
        a1.x += bflo(v0.z); a1.y += bfhi(v0.z);
        a1.z += bflo(v0.w); a1.w += bfhi(v0.w);
        if (j + 1 < c) {
            a0.x += bflo(v1.x); a0.y += bfhi(v1.x);
            a0.z += bflo(v1.y); a0.w += bfhi(v1.y);
            a1.x += bflo(v1.z); a1.y += bfhi(v1.z);
            a1.z += bflo(v1.w); a1.w += bfhi(v1.w);
        }
        if (j + 2 < c) {
            a0.x += bflo(v2.x); a0.y += bfhi(v2.x);
            a0.z += bflo(v2.y); a0.w += bfhi(v2.y);
            a1.x += bflo(v2.z); a1.y += bfhi(v2.z);
            a1.z += bflo(v2.w); a1.w += bfhi(v2.w);
        }
        if (j + 3 < c) {
            a0.x += bflo(v3.x); a0.y += bfhi(v3.x);
            a0.z += bflo(v3.y); a0.w += bfhi(v3.y);
            a1.x += bflo(v3.z); a1.y += bfhi(v3.z);
            a1.z += bflo(v3.w); a1.w += bfhi(v3.w);
        }
    }
    *(float4*)(out + ob)     = a0;
    *(float4*)(out + ob + 4) = a1;
}

// ===========================================================================
extern "C" void kernel_launch(void* const* d_in, const int* in_sizes, int n_in_cnt,
                              void* d_out, int out_size, void* d_ws, size_t ws_size,
                              hipStream_t stream) {
    const float* feats   = (const float*)d_in[0];
    const float* weight  = (const float*)d_in[1];
    const float* bias    = (const float*)d_in[2];
    const int*   bwd     = (const int*)d_in[3];
    const int*   in_idx  = (const int*)d_in[4];
    const int*   out_idx = (const int*)d_in[5];
    float*       out     = (float*)d_out;

    const int n_in  = in_sizes[0] / C_IN;      // 100000
    const int n_out = out_size / C_OUT;        // 800000
    const size_t P  = (size_t)KK * n_in;       // 2.7M records

    const int NCHA = (n_out + 2047) / 2048;    // 391 scan chunks

    // ---- workspace layout (int units) ----
    const size_t NOUTr   = ((size_t)n_out + 255) & ~(size_t)255;
    const size_t o_cnt   = 0;
    const size_t o_stv   = NOUTr;
    const size_t o_s1    = 2 * NOUTr;                    // sums (NCHA <= 512)
    const size_t o_ord   = (o_s1 + 512 + 255) & ~(size_t)255;      // ord (P)
    const size_t o_fbf   = (o_ord + P + 255) & ~(size_t)255;
    const size_t fbf_i   = ((size_t)(n_in + 16) * C_IN * 2 + 3) / 4;
    const size_t o_wfr   = (o_fbf + fbf_i + 255) & ~(size_t)255;
    const size_t wfr_i   = (size_t)KK * 4 * 64 * 8 * 2 / 4;
    const size_t o_ctr   = (o_wfr + wfr_i + 255) & ~(size_t)255;   // contrib

    const size_t ws_ints = ws_size / 4;
    size_t cap_recs = (ws_ints > o_ctr) ? (ws_ints - o_ctr) / 32 : 0;  // 128B/rec
    int kseg_max = (int)(cap_recs / (size_t)n_in);
    if (kseg_max > KK) kseg_max = KK;

    if (kseg_max < 1 || NCHA > 512) {
        // fallback: round-1 atomic path
        const int total4 = out_size / 4;
        hipLaunchKernelGGL(sic_init_bias, dim3(2048), dim3(256), 0, stream,
                           (float4*)out, (const float4*)bias, total4);
        hipLaunchKernelGGL(sic_scatter, dim3(160, KK), dim3(256), 0, stream,
                           feats, weight, bwd, in_idx, out_idx, out, n_in);
        return;
    }

    int* ws = (int*)d_ws;
    int* count  = ws + o_cnt;
    int* startv = ws + o_stv;
    int* sums   = ws + o_s1;
    int* ord    = ws + o_ord;
    short* featsbf = (short*)(ws + o_fbf);
    short* wfrag   = (short*)(ws + o_wfr);
    unsigned short* contrib = (unsigned short*)(ws + o_ctr);

    // one-time conversions
    hipLaunchKernelGGL(sic_fconv, dim3(((n_in + 1) * 4 + 255) / 256), dim3(256), 0, stream,
                       feats, featsbf, n_in);
    hipLaunchKernelGGL(sic_wconv, dim3((KK * 4 * 64 + 255) / 256), dim3(256), 0, stream,
                       weight, wfrag);

    const int ntiles  = (n_in + 15) / 16;
    const int gx_gemm = (ntiles + 3) / 4;      // one tile per wave

    // segment loop over k (single pass when contrib fits: kseg_max == 27)
    for (int k0 = 0; k0 < KK; k0 += kseg_max) {
        const int kseg = (KK - k0 < kseg_max) ? (KK - k0) : kseg_max;
        const int pseg = kseg * n_in;
        const int gp   = (pseg + 255) / 256;
        const int* oseg = out_idx + (size_t)k0 * n_in;

        hipLaunchKernelGGL(sic_zero, dim3(1024), dim3(512), 0, stream, count, n_out);
        hipLaunchKernelGGL(sic_hist3, dim3(gp), dim3(256), 0, stream,
                           oseg, count, ord, pseg);
        hipLaunchKernelGGL(sic_scanA, dim3(NCHA), dim3(512), 0, stream,
                           count, startv, sums, n_out);
        hipLaunchKernelGGL(sic_scan_small, dim3(1), dim3(512), 0, stream, sums, NCHA);
        hipLaunchKernelGGL(sic_addbackA, dim3(NCHA), dim3(512), 0, stream,
                           startv, sums, n_out);
        // MFMA + LDS transpose + nt full-row dst-sorted scatter (atomic-free)
        hipLaunchKernelGGL(sic_gemm3, dim3(gx_gemm, kseg), dim3(256), 0, stream,
                           in_idx, out_idx, bwd, ord, startv,
                           featsbf, wfrag, contrib, n_in, k0, n_in);
        // streaming reduce: 8 threads per output row, clamped-quad ILP
        hipLaunchKernelGGL(sic_reduce8, dim3((n_out * 8 + 255) / 256), dim3(256), 0, stream,
                           (const unsigned int*)contrib, startv, count, bias, out,
                           n_out, (k0 == 0) ? 1 : 0);
    }
}

// Round 13
// 346.792 us; speedup vs baseline: 1.3873x; 1.0219x over previous
//
#include <hip/hip_runtime.h>

#define C_IN  32
#define C_OUT 64
#define KK    27

using frag_ab = __attribute__((ext_vector_type(8))) short;  // 8 bf16
using frag_cd = __attribute__((ext_vector_type(4))) float;  // 4 fp32
using u32x4   = __attribute__((ext_vector_type(4))) unsigned int;  // nt-able

static __device__ inline unsigned short f2bf(float f) {   // RTNE f32->bf16
    unsigned u = __float_as_uint(f);
    return (unsigned short)((u + 0x7fffu + ((u >> 16) & 1u)) >> 16);
}
static __device__ inline unsigned pack2(float a, float b) {
    return (unsigned)f2bf(a) | ((unsigned)f2bf(b) << 16);
}
static __device__ inline float bflo(unsigned u) { return __uint_as_float(u << 16); }
static __device__ inline float bfhi(unsigned u) { return __uint_as_float(u & 0xffff0000u); }

// ===========================================================================
// Fallback path (round-1, passing) if workspace too small
// ===========================================================================
__global__ __launch_bounds__(256) void sic_init_bias(float4* __restrict__ out4,
                                                     const float4* __restrict__ bias4,
                                                     int total4) {
    int idx = blockIdx.x * 256 + threadIdx.x, stride = gridDim.x * 256;
    for (int i = idx; i < total4; i += stride) out4[i] = bias4[i & 15];
}

__global__ __launch_bounds__(256) void sic_scatter(
    const float* __restrict__ feats, const float* __restrict__ weight,
    const int* __restrict__ bwd, const int* __restrict__ in_idx,
    const int* __restrict__ out_idx, float* __restrict__ out, int n_in)
{
    const int k = blockIdx.y, lane = threadIdx.x & 63, wid = threadIdx.x >> 6;
    float w[C_IN];
    const float* wk = weight + k * (C_IN * C_OUT);
#pragma unroll
    for (int i = 0; i < C_IN; ++i) w[i] = wk[i * C_OUT + lane];
    const int waves_total = gridDim.x * 4;
    const long long base = (long long)k * n_in;
    for (int p = blockIdx.x * 4 + wid; p < n_in; p += waves_total) {
        int src = __builtin_amdgcn_readfirstlane(in_idx[base + p]);
        int dst = __builtin_amdgcn_readfirstlane(out_idx[base + p]);
        int row = __builtin_amdgcn_readfirstlane(bwd[src]);
        const float* f = feats + (long long)row * C_IN;
        float acc = 0.0f;
#pragma unroll
        for (int i = 0; i < C_IN; ++i) acc = fmaf(f[i], w[i], acc);
        atomicAdd(out + (long long)dst * C_OUT + lane, acc);
    }
}

// ===========================================================================
// Fused conversions: feats->bf16 (+ zero pad row) and weight->MFMA fragments
// blockIdx < fb_blocks: fconv; else: wconv.
// ===========================================================================
__global__ __launch_bounds__(256) void sic_fwconv(
    const float* __restrict__ feats, short* __restrict__ featsbf,
    const float* __restrict__ weight, short* __restrict__ wfrag,
    int n_in, int fb_blocks)
{
    if ((int)blockIdx.x < fb_blocks) {
        int t = blockIdx.x * 256 + threadIdx.x;
        if (t >= (n_in + 1) * 4) return;
        int row = t >> 2, c8 = (t & 3) * 8;
        uint4 v = {0u, 0u, 0u, 0u};
        if (row < n_in) {
            const float* fp = feats + (size_t)row * C_IN + c8;
            float4 f0 = ((const float4*)fp)[0];
            float4 f1 = ((const float4*)fp)[1];
            v.x = pack2(f0.x, f0.y);
            v.y = pack2(f0.z, f0.w);
            v.z = pack2(f1.x, f1.y);
            v.w = pack2(f1.z, f1.w);
        }
        ((uint4*)featsbf)[t] = v;
    } else {
        int t = (blockIdx.x - fb_blocks) * 256 + threadIdx.x;
        if (t >= KK * 4 * 64) return;
        int l = t & 63, nb = (t >> 6) & 3, k = t >> 8;
        int g = l >> 4, cl = l & 15;
        const float* wp = weight + (size_t)k * (C_IN * C_OUT) + nb * 16 + cl;
        float r[8];
#pragma unroll
        for (int j = 0; j < 8; ++j) r[j] = wp[(size_t)(g * 8 + j) * C_OUT];
        uint4 v = {pack2(r[0], r[1]), pack2(r[2], r[3]),
                   pack2(r[4], r[5]), pack2(r[6], r[7])};
        ((uint4*)wfrag)[t] = v;
    }
}

// histogram by destination + per-record ordinal (the atomic's return value)
__global__ __launch_bounds__(256) void sic_hist3(const int* __restrict__ out_idx_seg,
                                                 int* __restrict__ count,
                                                 int* __restrict__ ord, int pseg) {
    int i = blockIdx.x * 256 + threadIdx.x;
    if (i < pseg) {
        ord[i] = atomicAdd(&count[out_idx_seg[i]], 1);  // coalesced ord write
    }
}

// ---- scan step 1: per-chunk (2048) exclusive scan + chunk sums ----
__global__ __launch_bounds__(512) void sic_scanA(const int* __restrict__ in,
                                                 int* __restrict__ outExcl,
                                                 int* __restrict__ sums, int n) {
    __shared__ int sm[512];
    int tid = threadIdx.x;
    int base = blockIdx.x * 2048 + tid * 4;
    int e0 = (base + 0 < n) ? in[base + 0] : 0;
    int e1 = (base + 1 < n) ? in[base + 1] : 0;
    int e2 = (base + 2 < n) ? in[base + 2] : 0;
    int e3 = (base + 3 < n) ? in[base + 3] : 0;
    int s = e0 + e1 + e2 + e3;
    sm[tid] = s;
    __syncthreads();
    for (int off = 1; off < 512; off <<= 1) {
        int t = (tid >= off) ? sm[tid - off] : 0;
        __syncthreads();
        sm[tid] += t;
        __syncthreads();
    }
    int pre = sm[tid] - s;                   // exclusive within chunk
    if (base + 0 < n) outExcl[base + 0] = pre;
    if (base + 1 < n) outExcl[base + 1] = pre + e0;
    if (base + 2 < n) outExcl[base + 2] = pre + e0 + e1;
    if (base + 3 < n) outExcl[base + 3] = pre + e0 + e1 + e2;
    if (tid == 511) sums[blockIdx.x] = sm[511];
}

// ---- scan step 2 (fused): each block redundantly scans the <=512 chunk
// sums in LDS, then adds its chunk's exclusive offset. No inter-block dep. ----
__global__ __launch_bounds__(512) void sic_scanB(int* __restrict__ startv,
                                                 const int* __restrict__ sums,
                                                 int nch, int n) {
    __shared__ int sm[512];
    int tid = threadIdx.x;
    int e = (tid < nch) ? sums[tid] : 0;
    sm[tid] = e;
    __syncthreads();
    for (int off = 1; off < 512; off <<= 1) {
        int t = (tid >= off) ? sm[tid - off] : 0;
        __syncthreads();
        sm[tid] += t;
        __syncthreads();
    }
    int add = (blockIdx.x > 0) ? sm[blockIdx.x - 1] : 0;   // exclusive offset
    int base = blockIdx.x * 2048 + tid * 4;
#pragma unroll
    for (int i = 0; i < 4; ++i)
        if (base + i < n) startv[base + i] += add;
}

// ===========================================================================
// Phase A: per-k MFMA, TWO tiles per wave (independent gather chains ->
// 2x memory-level parallelism on the idx->bwd->featsbf latency chain).
// slot = startv[dst] + ord[rec]; LDS transpose; nt-store 128B rows.
// ===========================================================================
__global__ __launch_bounds__(256) void sic_gemm3b(
    const int* __restrict__ in_idx,     // global rulebook [KK][n_in]
    const int* __restrict__ out_idx,
    const int* __restrict__ bwd,
    const int* __restrict__ ord,        // segment-local [kseg*n_in]
    const int* __restrict__ startv,     // per-dst slot base
    const short* __restrict__ featsbf,  // [(n_in+pad)][32] bf16
    const short* __restrict__ wfrag,    // [KK][4][64][8] bf16
    unsigned short* __restrict__ contrib,
    int n_in, int k0, int zrow)
{
    __shared__ unsigned smU[4][2][16][40];  // [wave][tile][record][32+pad8]
    const int kk   = k0 + blockIdx.y;
    const int lane = threadIdx.x & 63;
    const int wid  = threadIdx.x >> 6;
    const int g = lane >> 4, cl = lane & 15;

    const frag_ab wa0 = *(const frag_ab*)(wfrag + ((size_t)(kk * 4 + 0) * 64 + lane) * 8);
    const frag_ab wa1 = *(const frag_ab*)(wfrag + ((size_t)(kk * 4 + 1) * 64 + lane) * 8);
    const frag_ab wa2 = *(const frag_ab*)(wfrag + ((size_t)(kk * 4 + 2) * 64 + lane) * 8);
    const frag_ab wa3 = *(const frag_ab*)(wfrag + ((size_t)(kk * 4 + 3) * 64 + lane) * 8);
    const frag_cd zf = {0.f, 0.f, 0.f, 0.f};

    const size_t gk  = (size_t)kk * n_in;            // rulebook base (global k)
    const size_t sk  = (size_t)blockIdx.y * n_in;    // ord base (segment-local)
    const int tp     = blockIdx.x * 4 + wid;         // tile pair for this wave
    const int t0     = tp * 2, t1 = t0 + 1;
    const int idx0   = t0 * 16 + cl;
    const int idx1   = t1 * 16 + cl;
    const bool v0 = idx0 < n_in, v1 = idx1 < n_in;

    // two independent gather chains (compiler interleaves the loads)
    int row0 = zrow, pos0 = 0, row1 = zrow, pos1 = 0;
    if (v0) {
        row0 = bwd[in_idx[gk + idx0]];
        pos0 = startv[out_idx[gk + idx0]] + ord[sk + idx0];
    }
    if (v1) {
        row1 = bwd[in_idx[gk + idx1]];
        pos1 = startv[out_idx[gk + idx1]] + ord[sk + idx1];
    }

    frag_ab b0 = *(const frag_ab*)(featsbf + (size_t)row0 * C_IN + g * 8);
    frag_ab b1 = *(const frag_ab*)(featsbf + (size_t)row1 * C_IN + g * 8);

    frag_cd d00 = __builtin_amdgcn_mfma_f32_16x16x32_bf16(wa0, b0, zf, 0, 0, 0);
    frag_cd d01 = __builtin_amdgcn_mfma_f32_16x16x32_bf16(wa1, b0, zf, 0, 0, 0);
    frag_cd d02 = __builtin_amdgcn_mfma_f32_16x16x32_bf16(wa2, b0, zf, 0, 0, 0);
    frag_cd d03 = __builtin_amdgcn_mfma_f32_16x16x32_bf16(wa3, b0, zf, 0, 0, 0);
    frag_cd d10 = __builtin_amdgcn_mfma_f32_16x16x32_bf16(wa0, b1, zf, 0, 0, 0);
    frag_cd d11 = __builtin_amdgcn_mfma_f32_16x16x32_bf16(wa1, b1, zf, 0, 0, 0);
    frag_cd d12 = __builtin_amdgcn_mfma_f32_16x16x32_bf16(wa2, b1, zf, 0, 0, 0);
    frag_cd d13 = __builtin_amdgcn_mfma_f32_16x16x32_bf16(wa3, b1, zf, 0, 0, 0);

    // transpose both tiles through LDS (record-major rows of 32 uints)
    smU[wid][0][cl][0  + g * 2 + 0] = pack2(d00[0], d00[1]);
    smU[wid][0][cl][0  + g * 2 + 1] = pack2(d00[2], d00[3]);
    smU[wid][0][cl][8  + g * 2 + 0] = pack2(d01[0], d01[1]);
    smU[wid][0][cl][8  + g * 2 + 1] = pack2(d01[2], d01[3]);
    smU[wid][0][cl][16 + g * 2 + 0] = pack2(d02[0], d02[1]);
    smU[wid][0][cl][16 + g * 2 + 1] = pack2(d02[2], d02[3]);
    smU[wid][0][cl][24 + g * 2 + 0] = pack2(d03[0], d03[1]);
    smU[wid][0][cl][24 + g * 2 + 1] = pack2(d03[2], d03[3]);
    smU[wid][1][cl][0  + g * 2 + 0] = pack2(d10[0], d10[1]);
    smU[wid][1][cl][0  + g * 2 + 1] = pack2(d10[2], d10[3]);
    smU[wid][1][cl][8  + g * 2 + 0] = pack2(d11[0], d11[1]);
    smU[wid][1][cl][8  + g * 2 + 1] = pack2(d11[2], d11[3]);
    smU[wid][1][cl][16 + g * 2 + 0] = pack2(d12[0], d12[1]);
    smU[wid][1][cl][16 + g * 2 + 1] = pack2(d12[2], d12[3]);
    smU[wid][1][cl][24 + g * 2 + 0] = pack2(d13[0], d13[1]);
    smU[wid][1][cl][24 + g * 2 + 1] = pack2(d13[2], d13[3]);
    __syncthreads();

    // write-out: per tile, 8 lanes per record, one contiguous 16B chunk each
#pragma unroll
    for (int p = 0; p < 2; ++p) {
        int r = (lane >> 3) + p * 8;          // record 0..15
        int c = lane & 7;                     // 16B chunk 0..7
        u32x4 va = {smU[wid][0][r][c * 4 + 0], smU[wid][0][r][c * 4 + 1],
                    smU[wid][0][r][c * 4 + 2], smU[wid][0][r][c * 4 + 3]};
        int pa = __shfl(pos0, r, 64);
        if (t0 * 16 + r < n_in) {
            __builtin_nontemporal_store(va,
                (u32x4*)(contrib + (size_t)pa * C_OUT + c * 8));
        }
        u32x4 vb = {smU[wid][1][r][c * 4 + 0], smU[wid][1][r][c * 4 + 1],
                    smU[wid][1][r][c * 4 + 2], smU[wid][1][r][c * 4 + 3]};
        int pb = __shfl(pos1, r, 64);
        if (t1 * 16 + r < n_in) {
            __builtin_nontemporal_store(vb,
                (u32x4*)(contrib + (size_t)pb * C_OUT + c * 8));
        }
    }
}

// ===========================================================================
// Phase B: streaming reduce, clamped-quad ILP (round-12, proven).
// ===========================================================================
__global__ __launch_bounds__(256) void sic_reduce8(
    const unsigned int* __restrict__ contribU,  // row r at contribU[r*32]
    const int* __restrict__ startv, const int* __restrict__ count,
    const float* __restrict__ bias, float* __restrict__ out,
    int n_out, int first)
{
    int t = blockIdx.x * 256 + threadIdx.x;
    int dst = t >> 3, c8 = t & 7;
    if (dst >= n_out) return;
    int s = startv[dst], c = count[dst];

    size_t ob = (size_t)dst * C_OUT + c8 * 8;
    float4 a0, a1;
    if (first) {
        a0 = *(const float4*)(bias + c8 * 8);
        a1 = *(const float4*)(bias + c8 * 8 + 4);
    } else {
        a0 = *(const float4*)(out + ob);
        a1 = *(const float4*)(out + ob + 4);
    }
    const u32x4* p = (const u32x4*)(contribU + (size_t)s * 32) + c8;
    for (int j = 0; j < c; j += 4) {
        int cm = c - 1;
        int j1 = (j + 1 < cm) ? j + 1 : cm;
        int j2 = (j + 2 < cm) ? j + 2 : cm;
        int j3 = (j + 3 < cm) ? j + 3 : cm;
        u32x4 v0 = __builtin_nontemporal_load(&p[(size_t)j  * 8]);
        u32x4 v1 = __builtin_nontemporal_load(&p[(size_t)j1 * 8]);
        u32x4 v2 = __builtin_nontemporal_load(&p[(size_t)j2 * 8]);
        u32x4 v3 = __builtin_nontemporal_load(&p[(size_t)j3 * 8]);
        a0.x += bflo(v0.x); a0.y += bfhi(v0.x);
        a0.z += bflo(v0.y); a0.w += bfhi(v0.y);
        a1.x += bflo(v0.z); a1.y += bfhi(v0.z);
        a1.z += bflo(v0.w); a1.w += bfhi(v0.w);
        if (j + 1 < c) {
            a0.x += bflo(v1.x); a0.y += bfhi(v1.x);
            a0.z += bflo(v1.y); a0.w += bfhi(v1.y);
            a1.x += bflo(v1.z); a1.y += bfhi(v1.z);
            a1.z += bflo(v1.w); a1.w += bfhi(v1.w);
        }
        if (j + 2 < c) {
            a0.x += bflo(v2.x); a0.y += bfhi(v2.x);
            a0.z += bflo(v2.y); a0.w += bfhi(v2.y);
            a1.x += bflo(v2.z); a1.y += bfhi(v2.z);
            a1.z += bflo(v2.w); a1.w += bfhi(v2.w);
        }
        if (j + 3 < c) {
            a0.x += bflo(v3.x); a0.y += bfhi(v3.x);
            a0.z += bflo(v3.y); a0.w += bfhi(v3.y);
            a1.x += bflo(v3.z); a1.y += bfhi(v3.z);
            a1.z += bflo(v3.w); a1.w += bfhi(v3.w);
        }
    }
    *(float4*)(out + ob)     = a0;
    *(float4*)(out + ob + 4) = a1;
}

// ===========================================================================
extern "C" void kernel_launch(void* const* d_in, const int* in_sizes, int n_in_cnt,
                              void* d_out, int out_size, void* d_ws, size_t ws_size,
                              hipStream_t stream) {
    const float* feats   = (const float*)d_in[0];
    const float* weight  = (const float*)d_in[1];
    const float* bias    = (const float*)d_in[2];
    const int*   bwd     = (const int*)d_in[3];
    const int*   in_idx  = (const int*)d_in[4];
    const int*   out_idx = (const int*)d_in[5];
    float*       out     = (float*)d_out;

    const int n_in  = in_sizes[0] / C_IN;      // 100000
    const int n_out = out_size / C_OUT;        // 800000
    const size_t P  = (size_t)KK * n_in;       // 2.7M records

    const int NCHA = (n_out + 2047) / 2048;    // 391 scan chunks

    // ---- workspace layout (int units) ----
    const size_t NOUTr   = ((size_t)n_out + 255) & ~(size_t)255;
    const size_t o_cnt   = 0;
    const size_t o_stv   = NOUTr;
    const size_t o_s1    = 2 * NOUTr;                    // sums (NCHA <= 512)
    const size_t o_ord   = (o_s1 + 512 + 255) & ~(size_t)255;      // ord (P)
    const size_t o_fbf   = (o_ord + P + 255) & ~(size_t)255;
    const size_t fbf_i   = ((size_t)(n_in + 16) * C_IN * 2 + 3) / 4;
    const size_t o_wfr   = (o_fbf + fbf_i + 255) & ~(size_t)255;
    const size_t wfr_i   = (size_t)KK * 4 * 64 * 8 * 2 / 4;
    const size_t o_ctr   = (o_wfr + wfr_i + 255) & ~(size_t)255;   // contrib

    const size_t ws_ints = ws_size / 4;
    size_t cap_recs = (ws_ints > o_ctr) ? (ws_ints - o_ctr) / 32 : 0;  // 128B/rec
    int kseg_max = (int)(cap_recs / (size_t)n_in);
    if (kseg_max > KK) kseg_max = KK;

    if (kseg_max < 1 || NCHA > 512) {
        // fallback: round-1 atomic path
        const int total4 = out_size / 4;
        hipLaunchKernelGGL(sic_init_bias, dim3(2048), dim3(256), 0, stream,
                           (float4*)out, (const float4*)bias, total4);
        hipLaunchKernelGGL(sic_scatter, dim3(160, KK), dim3(256), 0, stream,
                           feats, weight, bwd, in_idx, out_idx, out, n_in);
        return;
    }

    int* ws = (int*)d_ws;
    int* count  = ws + o_cnt;
    int* startv = ws + o_stv;
    int* sums   = ws + o_s1;
    int* ord    = ws + o_ord;
    short* featsbf = (short*)(ws + o_fbf);
    short* wfrag   = (short*)(ws + o_wfr);
    unsigned short* contrib = (unsigned short*)(ws + o_ctr);

    // fused one-time conversions (fconv blocks, then wconv blocks)
    const int fb_blocks = ((n_in + 1) * 4 + 255) / 256;
    const int wb_blocks = (KK * 4 * 64 + 255) / 256;
    hipLaunchKernelGGL(sic_fwconv, dim3(fb_blocks + wb_blocks), dim3(256), 0, stream,
                       feats, featsbf, weight, wfrag, n_in, fb_blocks);

    const int ntiles  = (n_in + 15) / 16;
    const int gx_gemm = (ntiles + 7) / 8;      // 4 waves x 2 tiles per block

    // segment loop over k (single pass when contrib fits: kseg_max == 27)
    for (int k0 = 0; k0 < KK; k0 += kseg_max) {
        const int kseg = (KK - k0 < kseg_max) ? (KK - k0) : kseg_max;
        const int pseg = kseg * n_in;
        const int gp   = (pseg + 255) / 256;
        const int* oseg = out_idx + (size_t)k0 * n_in;

        hipMemsetAsync(count, 0, (size_t)n_out * sizeof(int), stream);
        hipLaunchKernelGGL(sic_hist3, dim3(gp), dim3(256), 0, stream,
                           oseg, count, ord, pseg);
        hipLaunchKernelGGL(sic_scanA, dim3(NCHA), dim3(512), 0, stream,
                           count, startv, sums, n_out);
        hipLaunchKernelGGL(sic_scanB, dim3(NCHA), dim3(512), 0, stream,
                           startv, sums, NCHA, n_out);
        // MFMA (2 tiles/wave) + LDS transpose + nt full-row scatter
        hipLaunchKernelGGL(sic_gemm3b, dim3(gx_gemm, kseg), dim3(256), 0, stream,
                           in_idx, out_idx, bwd, ord, startv,
                           featsbf, wfrag, contrib, n_in, k0, n_in);
        // streaming reduce: 8 threads per output row, clamped-quad ILP
        hipLaunchKernelGGL(sic_reduce8, dim3((n_out * 8 + 255) / 256), dim3(256), 0, stream,
                           (const unsigned int*)contrib, startv, count, bias, out,
                           n_out, (k0 == 0) ? 1 : 0);
    }
}